// Round 3
// baseline (85447.302 us; speedup 1.0000x reference)
//
#include <hip/hip_runtime.h>
#include <hip/hip_bf16.h>

#define BB 64
#define TT 2048
#define HH 256
#define H4 1024
#define NC 10
#define NWG1 128          // layer-1 WGs
#define NWGT 256          // total WGs (128 layer-1 + 128 layer-2)
#define BBHH (BB * HH)

struct __align__(128) Line { unsigned v; unsigned pad[31]; };  // one cacheline

__device__ __forceinline__ float sigmoidf_(float x) {
    return 1.0f / (1.0f + expf(-x));
}

// ---------------------------------------------------------------------------
// gx GEMM (layer 1 input contribution only):
// gx[tc][n][b] = sum_k x[b][t0+tc][k] * W[n][k] + bih[n] + bhh[n]
// ---------------------------------------------------------------------------
__global__ __launch_bounds__(256, 2)
void gemm_gx(const float* __restrict__ A, const float* __restrict__ W,
             const float* __restrict__ bias1, const float* __restrict__ bias2,
             float* __restrict__ gx, int t0)
{
    __shared__ float As[8][132];
    __shared__ float Bs[8][132];
    const int tid = threadIdx.x;
    const int m0 = blockIdx.y * 128, n0 = blockIdx.x * 128;
    const int tx = tid & 15, ty = tid >> 4;

    float acc[8][8];
#pragma unroll
    for (int i = 0; i < 8; i++)
#pragma unroll
        for (int j = 0; j < 8; j++) acc[i][j] = 0.f;

    const int mL = tid >> 1, half = tid & 1;
    const int gm = m0 + mL;
    const int b = gm & 63, tc = gm >> 6;
    const float* arow = A + ((size_t)b * TT + t0 + tc) * 256;
    const float* brow = W + (size_t)(n0 + mL) * 256;

    for (int k0 = 0; k0 < 256; k0 += 8) {
        float4 av = *(const float4*)(arow + k0 + half * 4);
        float4 bv = *(const float4*)(brow + k0 + half * 4);
        __syncthreads();
        As[half * 4 + 0][mL] = av.x; As[half * 4 + 1][mL] = av.y;
        As[half * 4 + 2][mL] = av.z; As[half * 4 + 3][mL] = av.w;
        Bs[half * 4 + 0][mL] = bv.x; Bs[half * 4 + 1][mL] = bv.y;
        Bs[half * 4 + 2][mL] = bv.z; Bs[half * 4 + 3][mL] = bv.w;
        __syncthreads();
#pragma unroll
        for (int k = 0; k < 8; k++) {
            float a[8], w[8];
            *(float4*)&a[0] = *(const float4*)&As[k][ty * 8];
            *(float4*)&a[4] = *(const float4*)&As[k][ty * 8 + 4];
            *(float4*)&w[0] = *(const float4*)&Bs[k][tx * 8];
            *(float4*)&w[4] = *(const float4*)&Bs[k][tx * 8 + 4];
#pragma unroll
            for (int i = 0; i < 8; i++)
#pragma unroll
                for (int j = 0; j < 8; j++) acc[i][j] += a[i] * w[j];
        }
    }
#pragma unroll
    for (int i = 0; i < 8; i++) {
        int m = m0 + ty * 8 + i;
        int bb = m & 63, tcc = m >> 6;
#pragma unroll
        for (int j = 0; j < 8; j++) {
            int n = n0 + tx * 8 + j;
            gx[((size_t)tcc * H4 + n) * 64 + bb] = acc[i][j] + bias1[n] + bias2[n];
        }
    }
}

// ---------------------------------------------------------------------------
// Merged persistent kernel, flag-based parallel device barrier.
// WGs [0,128) = layer 1, [128,256) = layer 2 (one step behind).
// ---------------------------------------------------------------------------
__global__ __launch_bounds__(256, 1)
void lstm_rec2(const float* __restrict__ gx, const float* __restrict__ Whh0,
               const float* __restrict__ Wih1, const float* __restrict__ Whh1,
               const float* __restrict__ bih1, const float* __restrict__ bhh1,
               float* __restrict__ h1r, float* __restrict__ h2r,
               float* __restrict__ c1b, float* __restrict__ c2b,
               Line* __restrict__ flags, Line* __restrict__ go,
               int t0, int l1cnt, int niter)
{
    __shared__ float Wl[2][8][264];   // [0]=Whh0 (L1) or Wih1 (L2); [1]=Whh1 (L2)
    __shared__ float hA[64][260];     // h1_{i-1} stage (both layers)
    __shared__ float hB[64][260];     // h2_{i-2} stage (layer 2 only)

    const int tid = threadIdx.x;
    const int wg = blockIdx.x;
    const bool isL2 = wg >= NWG1;
    const int u0 = (isL2 ? wg - NWG1 : wg) * 2;
    const int r = tid & 7, duo = tid >> 3;
    const int b0 = 2 * duo, b1 = 2 * duo + 1;
    const int ul = r & 1;
    const int grow = (r >> 1) * HH + u0 + ul;

    {
        const float* W0 = isL2 ? Wih1 : Whh0;
#pragma unroll
        for (int rep = 0; rep < 2; rep++) {
            int idx = rep * 256 + tid;
            int row = idx >> 6, q = idx & 63;
            int gr = (row >> 1) * HH + u0 + (row & 1);
            *(float4*)&Wl[0][row][q * 4] = *(const float4*)(W0 + (size_t)gr * 256 + q * 4);
            if (isL2)
                *(float4*)&Wl[1][row][q * 4] = *(const float4*)(Whh1 + (size_t)gr * 256 + q * 4);
        }
    }
    float bs = 0.f;
    if (isL2) bs = bih1[grow] + bhh1[grow];

    float* cbuf = isL2 ? c2b : c1b;
    float c0 = 0.f, c1 = 0.f;
    if (r < 2) {
        c0 = cbuf[b0 * HH + u0 + r];
        c1 = cbuf[b1 * HH + u0 + r];
    }

    const int lane = tid & 63;
    const int sbase = ((lane >> 3) << 3) + ul;

    for (int j = 0; j < niter; j++) {
        const int i = t0 + j;
        const bool actL1 = (!isL2) && (j < l1cnt);
        const bool actL2 = isL2 && (i >= 1);

        float gxa = 0.f, gxb_ = 0.f;
        if (actL1) {
            gxa  = gx[((size_t)j * H4 + grow) * BB + b0];
            gxb_ = gx[((size_t)j * H4 + grow) * BB + b1];
        }

        const float* srcA = h1r + (size_t)((i + 1) & 1) * BBHH;
        const float* srcB = h2r + (size_t)(i & 1) * BBHH;
#pragma unroll
        for (int rep = 0; rep < 16; rep++) {
            int idx = rep * 256 + tid;
            int bb = idx >> 6, q = idx & 63;
            float4 vA = *(const float4*)(srcA + bb * HH + q * 4);
            *(float4*)&hA[bb][q * 4] = vA;
            if (isL2) {
                float4 vB = *(const float4*)(srcB + bb * HH + q * 4);
                *(float4*)&hB[bb][q * 4] = vB;
            }
        }
        __syncthreads();

        float pre0 = 0.f, pre1 = 0.f;
        if (actL1) {
            float a0 = 0.f, a1 = 0.f;
#pragma unroll 8
            for (int k = 0; k < 256; k += 4) {
                float4 w  = *(const float4*)&Wl[0][r][k];
                float4 x0 = *(const float4*)&hA[b0][k];
                float4 x1 = *(const float4*)&hA[b1][k];
                a0 += w.x * x0.x + w.y * x0.y + w.z * x0.z + w.w * x0.w;
                a1 += w.x * x1.x + w.y * x1.y + w.z * x1.z + w.w * x1.w;
            }
            pre0 = a0 + gxa;
            pre1 = a1 + gxb_;
        } else if (actL2) {
            float a0 = 0.f, a1 = 0.f;
#pragma unroll 4
            for (int k = 0; k < 256; k += 4) {
                float4 wI  = *(const float4*)&Wl[0][r][k];
                float4 wH  = *(const float4*)&Wl[1][r][k];
                float4 xA0 = *(const float4*)&hA[b0][k];
                float4 xA1 = *(const float4*)&hA[b1][k];
                float4 xB0 = *(const float4*)&hB[b0][k];
                float4 xB1 = *(const float4*)&hB[b1][k];
                a0 += wI.x * xA0.x + wI.y * xA0.y + wI.z * xA0.z + wI.w * xA0.w
                    + wH.x * xB0.x + wH.y * xB0.y + wH.z * xB0.z + wH.w * xB0.w;
                a1 += wI.x * xA1.x + wI.y * xA1.y + wI.z * xA1.z + wI.w * xA1.w
                    + wH.x * xB1.x + wH.y * xB1.y + wH.z * xB1.z + wH.w * xB1.w;
            }
            pre0 = a0 + bs;
            pre1 = a1 + bs;
        }

        if (actL1 || actL2) {
            float i0 = __shfl(pre0, sbase + 0, 64);
            float f0 = __shfl(pre0, sbase + 2, 64);
            float g0 = __shfl(pre0, sbase + 4, 64);
            float o0 = __shfl(pre0, sbase + 6, 64);
            float i1 = __shfl(pre1, sbase + 0, 64);
            float f1 = __shfl(pre1, sbase + 2, 64);
            float g1 = __shfl(pre1, sbase + 4, 64);
            float o1 = __shfl(pre1, sbase + 6, 64);

            if (r < 2) {
                float ia = sigmoidf_(i0), fa = sigmoidf_(f0);
                float ga = tanhf(g0),     oa = sigmoidf_(o0);
                c0 = fa * c0 + ia * ga;
                float h0 = oa * tanhf(c0);
                float ib = sigmoidf_(i1), fb = sigmoidf_(f1);
                float gb = tanhf(g1),     ob = sigmoidf_(o1);
                c1 = fb * c1 + ib * gb;
                float h1n = ob * tanhf(c1);
                float* dst = actL1 ? (h1r + (size_t)(i & 1) * BBHH)
                                   : (h2r + (size_t)((i + 1) & 1) * BBHH);
                dst[b0 * HH + u0 + r] = h0;
                dst[b1 * HH + u0 + r] = h1n;
            }
        }

        // ---- flag-based parallel device barrier ----
        const unsigned target = (unsigned)j + 1u;
        __syncthreads();
        if (tid == 0) {
            __threadfence();
            __hip_atomic_store(&flags[wg].v, target, __ATOMIC_RELEASE,
                               __HIP_MEMORY_SCOPE_AGENT);
        }
        if (wg == 0) {
            // parallel detection: thread tid watches flags[tid] (NWGT == blockDim)
            while (__hip_atomic_load(&flags[tid].v, __ATOMIC_ACQUIRE,
                                     __HIP_MEMORY_SCOPE_AGENT) < target)
                __builtin_amdgcn_s_sleep(1);
            __syncthreads();
            if (tid < 8) {
                __threadfence();
                __hip_atomic_store(&go[tid].v, target, __ATOMIC_RELEASE,
                                   __HIP_MEMORY_SCOPE_AGENT);
            }
            __syncthreads();
        } else {
            if (tid == 0) {
                while (__hip_atomic_load(&go[wg & 7].v, __ATOMIC_ACQUIRE,
                                         __HIP_MEMORY_SCOPE_AGENT) < target)
                    __builtin_amdgcn_s_sleep(2);
            }
            __syncthreads();
        }
    }

    if (r < 2) {
        cbuf[b0 * HH + u0 + r] = c0;
        cbuf[b1 * HH + u0 + r] = c1;
    }
}

// ---------------------------------------------------------------------------
__global__ void fc_kernel(const float* __restrict__ h2,
                          const float* __restrict__ Wfc,
                          const float* __restrict__ bfc,
                          float* __restrict__ out)
{
    __shared__ float hs[256];
    int b = blockIdx.x, tid = threadIdx.x;
    hs[tid] = h2[b * HH + tid];
    __syncthreads();
    if (tid < NC) {
        float s = bfc[tid];
        for (int k = 0; k < 256; k++) s += hs[k] * Wfc[tid * 256 + k];
        out[b * NC + tid] = s;
    }
}

// ---------------------------------------------------------------------------
extern "C" void kernel_launch(void* const* d_in, const int* in_sizes, int n_in,
                              void* d_out, int out_size, void* d_ws, size_t ws_size,
                              hipStream_t stream)
{
    const float* x    = (const float*)d_in[0];
    const float* Wih0 = (const float*)d_in[1];
    const float* Whh0 = (const float*)d_in[2];
    const float* bih0 = (const float*)d_in[3];
    const float* bhh0 = (const float*)d_in[4];
    const float* Wih1 = (const float*)d_in[5];
    const float* Whh1 = (const float*)d_in[6];
    const float* bih1 = (const float*)d_in[7];
    const float* bhh1 = (const float*)d_in[8];
    const float* Wfc  = (const float*)d_in[9];
    const float* bfc  = (const float*)d_in[10];

    float* ws = (float*)d_ws;

    int TC = TT;
    while (TC > 128) {
        size_t need = ((size_t)TC * BB * H4 + 6 * BBHH + 3000 * 32) * 4;
        if (need <= ws_size) break;
        TC >>= 1;
    }

    float* gxb = ws;
    float* h1r = gxb + (size_t)TC * BB * H4;
    float* h2r = h1r + 2 * BBHH;
    float* c1b = h2r + 2 * BBHH;
    float* c2b = c1b + BBHH;
    uintptr_t fp = ((uintptr_t)(c2b + BBHH) + 127) & ~(uintptr_t)127;
    Line* flags = (Line*)fp;
    Line* go    = flags + NWGT;

    // zero rings + cell states once
    hipMemsetAsync(h1r, 0, (size_t)6 * BBHH * 4, stream);

    const int nchunk = TT / TC;
    for (int ch = 0; ch < nchunk; ch++) {
        int t0 = ch * TC;
        dim3 gg(8, TC * 64 / 128);
        gemm_gx<<<gg, 256, 0, stream>>>(x, Wih0, bih0, bhh0, gxb, t0);
        hipMemsetAsync(flags, 0, sizeof(Line) * (NWGT + 8), stream);
        int last = (ch == nchunk - 1) ? 1 : 0;
        lstm_rec2<<<NWGT, 256, 0, stream>>>(gxb, Whh0, Wih1, Whh1, bih1, bhh1,
                                            h1r, h2r, c1b, c2b, flags, go,
                                            t0, TC, TC + last);
    }

    fc_kernel<<<BB, 256, 0, stream>>>(h2r + (size_t)((TT - 1) & 1) * BBHH,
                                      Wfc, bfc, (float*)d_out);
}

// Round 4
// 35188.956 us; speedup vs baseline: 2.4282x; 2.4282x over previous
//
#include <hip/hip_runtime.h>
#include <hip/hip_bf16.h>

#define BB 64
#define TT 2048
#define HH 256
#define H4 1024
#define NC 10
#define NWG1 128          // layer-1 WGs
#define NWGT 256          // total WGs (128 layer-1 + 128 layer-2)
#define NLEAF 16
#define BBHH (BB * HH)

struct __align__(128) Line { unsigned v; unsigned pad[31]; };  // one cacheline

__device__ __forceinline__ float sigmoidf_(float x) {
    return 1.0f / (1.0f + expf(-x));
}

// ---------------------------------------------------------------------------
// gx GEMM (layer 1 input contribution only):
// gx[tc][n][b] = sum_k x[b][t0+tc][k] * W[n][k] + bih[n] + bhh[n]
// ---------------------------------------------------------------------------
__global__ __launch_bounds__(256, 2)
void gemm_gx(const float* __restrict__ A, const float* __restrict__ W,
             const float* __restrict__ bias1, const float* __restrict__ bias2,
             float* __restrict__ gx, int t0)
{
    __shared__ float As[8][132];
    __shared__ float Bs[8][132];
    const int tid = threadIdx.x;
    const int m0 = blockIdx.y * 128, n0 = blockIdx.x * 128;
    const int tx = tid & 15, ty = tid >> 4;

    float acc[8][8];
#pragma unroll
    for (int i = 0; i < 8; i++)
#pragma unroll
        for (int j = 0; j < 8; j++) acc[i][j] = 0.f;

    const int mL = tid >> 1, half = tid & 1;
    const int gm = m0 + mL;
    const int b = gm & 63, tc = gm >> 6;
    const float* arow = A + ((size_t)b * TT + t0 + tc) * 256;
    const float* brow = W + (size_t)(n0 + mL) * 256;

    for (int k0 = 0; k0 < 256; k0 += 8) {
        float4 av = *(const float4*)(arow + k0 + half * 4);
        float4 bv = *(const float4*)(brow + k0 + half * 4);
        __syncthreads();
        As[half * 4 + 0][mL] = av.x; As[half * 4 + 1][mL] = av.y;
        As[half * 4 + 2][mL] = av.z; As[half * 4 + 3][mL] = av.w;
        Bs[half * 4 + 0][mL] = bv.x; Bs[half * 4 + 1][mL] = bv.y;
        Bs[half * 4 + 2][mL] = bv.z; Bs[half * 4 + 3][mL] = bv.w;
        __syncthreads();
#pragma unroll
        for (int k = 0; k < 8; k++) {
            float a[8], w[8];
            *(float4*)&a[0] = *(const float4*)&As[k][ty * 8];
            *(float4*)&a[4] = *(const float4*)&As[k][ty * 8 + 4];
            *(float4*)&w[0] = *(const float4*)&Bs[k][tx * 8];
            *(float4*)&w[4] = *(const float4*)&Bs[k][tx * 8 + 4];
#pragma unroll
            for (int i = 0; i < 8; i++)
#pragma unroll
                for (int j = 0; j < 8; j++) acc[i][j] += a[i] * w[j];
        }
    }
#pragma unroll
    for (int i = 0; i < 8; i++) {
        int m = m0 + ty * 8 + i;
        int bb = m & 63, tcc = m >> 6;
#pragma unroll
        for (int j = 0; j < 8; j++) {
            int n = n0 + tx * 8 + j;
            gx[((size_t)tcc * H4 + n) * 64 + bb] = acc[i][j] + bias1[n] + bias2[n];
        }
    }
}

// ---------------------------------------------------------------------------
// Merged persistent kernel. WGs [0,128) = layer 1, [128,256) = layer 2
// (one step behind). Barrier: hierarchical relaxed-atomic arrival
// (16 leaves + root), relaxed poll on shared phase line, ONE acquire fence
// per WG per step (no per-iteration buffer_inv), ONE release fence before
// arrival (small dirty set -> cheap wbl2).
// ---------------------------------------------------------------------------
__global__ __launch_bounds__(256, 1)
void lstm_rec2(const float* __restrict__ gx, const float* __restrict__ Whh0,
               const float* __restrict__ Wih1, const float* __restrict__ Whh1,
               const float* __restrict__ bih1, const float* __restrict__ bhh1,
               float* __restrict__ h1r, float* __restrict__ h2r,
               float* __restrict__ c1b, float* __restrict__ c2b,
               Line* __restrict__ leaf, Line* __restrict__ rootc,
               Line* __restrict__ phl,
               int t0, int l1cnt, int niter)
{
    __shared__ float Wl[2][8][264];   // [0]=Whh0 (L1) or Wih1 (L2); [1]=Whh1 (L2)
    __shared__ float hA[64][260];     // h1_{i-1} stage (both layers)
    __shared__ float hB[64][260];     // h2_{i-2} stage (layer 2 only)

    const int tid = threadIdx.x;
    const int wg = blockIdx.x;
    const bool isL2 = wg >= NWG1;
    const int u0 = (isL2 ? wg - NWG1 : wg) * 2;
    const int r = tid & 7, duo = tid >> 3;
    const int b0 = 2 * duo, b1 = 2 * duo + 1;
    const int ul = r & 1;
    const int grow = (r >> 1) * HH + u0 + ul;

    {
        const float* W0 = isL2 ? Wih1 : Whh0;
#pragma unroll
        for (int rep = 0; rep < 2; rep++) {
            int idx = rep * 256 + tid;
            int row = idx >> 6, q = idx & 63;
            int gr = (row >> 1) * HH + u0 + (row & 1);
            *(float4*)&Wl[0][row][q * 4] = *(const float4*)(W0 + (size_t)gr * 256 + q * 4);
            if (isL2)
                *(float4*)&Wl[1][row][q * 4] = *(const float4*)(Whh1 + (size_t)gr * 256 + q * 4);
        }
    }
    float bs = 0.f;
    if (isL2) bs = bih1[grow] + bhh1[grow];

    float* cbuf = isL2 ? c2b : c1b;
    float c0 = 0.f, c1 = 0.f;
    if (r < 2) {
        c0 = cbuf[b0 * HH + u0 + r];
        c1 = cbuf[b1 * HH + u0 + r];
    }

    const int lane = tid & 63;
    const int sbase = ((lane >> 3) << 3) + ul;

    for (int j = 0; j < niter; j++) {
        const int i = t0 + j;
        const bool actL1 = (!isL2) && (j < l1cnt);
        const bool actL2 = isL2 && (i >= 1);

        // prefetch gx into registers BEFORE the barrier's acquire fence
        float gxa = 0.f, gxb_ = 0.f;
        if (actL1) {
            gxa  = gx[((size_t)j * H4 + grow) * BB + b0];
            gxb_ = gx[((size_t)j * H4 + grow) * BB + b1];
        }

        const float* srcA = h1r + (size_t)((i + 1) & 1) * BBHH;
        const float* srcB = h2r + (size_t)(i & 1) * BBHH;
#pragma unroll
        for (int rep = 0; rep < 16; rep++) {
            int idx = rep * 256 + tid;
            int bb = idx >> 6, q = idx & 63;
            float4 vA = *(const float4*)(srcA + bb * HH + q * 4);
            *(float4*)&hA[bb][q * 4] = vA;
            if (isL2) {
                float4 vB = *(const float4*)(srcB + bb * HH + q * 4);
                *(float4*)&hB[bb][q * 4] = vB;
            }
        }
        __syncthreads();

        float pre0 = 0.f, pre1 = 0.f;
        if (actL1) {
            float a0 = 0.f, a1 = 0.f;
#pragma unroll 8
            for (int k = 0; k < 256; k += 4) {
                float4 w  = *(const float4*)&Wl[0][r][k];
                float4 x0 = *(const float4*)&hA[b0][k];
                float4 x1 = *(const float4*)&hA[b1][k];
                a0 += w.x * x0.x + w.y * x0.y + w.z * x0.z + w.w * x0.w;
                a1 += w.x * x1.x + w.y * x1.y + w.z * x1.z + w.w * x1.w;
            }
            pre0 = a0 + gxa;
            pre1 = a1 + gxb_;
        } else if (actL2) {
            float a0 = 0.f, a1 = 0.f;
#pragma unroll 4
            for (int k = 0; k < 256; k += 4) {
                float4 wI  = *(const float4*)&Wl[0][r][k];
                float4 wH  = *(const float4*)&Wl[1][r][k];
                float4 xA0 = *(const float4*)&hA[b0][k];
                float4 xA1 = *(const float4*)&hA[b1][k];
                float4 xB0 = *(const float4*)&hB[b0][k];
                float4 xB1 = *(const float4*)&hB[b1][k];
                a0 += wI.x * xA0.x + wI.y * xA0.y + wI.z * xA0.z + wI.w * xA0.w
                    + wH.x * xB0.x + wH.y * xB0.y + wH.z * xB0.z + wH.w * xB0.w;
                a1 += wI.x * xA1.x + wI.y * xA1.y + wI.z * xA1.z + wI.w * xA1.w
                    + wH.x * xB1.x + wH.y * xB1.y + wH.z * xB1.z + wH.w * xB1.w;
            }
            pre0 = a0 + bs;
            pre1 = a1 + bs;
        }

        if (actL1 || actL2) {
            float i0 = __shfl(pre0, sbase + 0, 64);
            float f0 = __shfl(pre0, sbase + 2, 64);
            float g0 = __shfl(pre0, sbase + 4, 64);
            float o0 = __shfl(pre0, sbase + 6, 64);
            float i1 = __shfl(pre1, sbase + 0, 64);
            float f1 = __shfl(pre1, sbase + 2, 64);
            float g1 = __shfl(pre1, sbase + 4, 64);
            float o1 = __shfl(pre1, sbase + 6, 64);

            if (r < 2) {
                float ia = sigmoidf_(i0), fa = sigmoidf_(f0);
                float ga = tanhf(g0),     oa = sigmoidf_(o0);
                c0 = fa * c0 + ia * ga;
                float h0 = oa * tanhf(c0);
                float ib = sigmoidf_(i1), fb = sigmoidf_(f1);
                float gb = tanhf(g1),     ob = sigmoidf_(o1);
                c1 = fb * c1 + ib * gb;
                float h1n = ob * tanhf(c1);
                float* dst = actL1 ? (h1r + (size_t)(i & 1) * BBHH)
                                   : (h2r + (size_t)((i + 1) & 1) * BBHH);
                dst[b0 * HH + u0 + r] = h0;
                dst[b1 * HH + u0 + r] = h1n;
            }
        }

        // ---- device barrier: relaxed hierarchical arrival, fences once ----
        const unsigned target = (unsigned)j + 1u;
        __syncthreads();   // all h stores issued & complete to cache
        if (tid == 0) {
            // make this WG's h stores agent-visible (wbl2; small dirty set)
            __builtin_amdgcn_fence(__ATOMIC_RELEASE, "agent");
            unsigned a = __hip_atomic_fetch_add(&leaf[wg & (NLEAF - 1)].v, 1u,
                                                __ATOMIC_RELAXED,
                                                __HIP_MEMORY_SCOPE_AGENT);
            if (a == target * (NWGT / NLEAF) - 1u) {
                unsigned rr = __hip_atomic_fetch_add(&rootc->v, 1u,
                                                     __ATOMIC_RELAXED,
                                                     __HIP_MEMORY_SCOPE_AGENT);
                if (rr == target * NLEAF - 1u) {
                    __hip_atomic_store(&phl->v, target, __ATOMIC_RELAXED,
                                       __HIP_MEMORY_SCOPE_AGENT);
                }
            }
            // relaxed poll: NO per-iteration cache invalidate
            while (__hip_atomic_load(&phl->v, __ATOMIC_RELAXED,
                                     __HIP_MEMORY_SCOPE_AGENT) < target)
                __builtin_amdgcn_s_sleep(1);
            // one acquire per step: invalidate stale h lines
            __builtin_amdgcn_fence(__ATOMIC_ACQUIRE, "agent");
        }
        __syncthreads();
    }

    if (r < 2) {
        cbuf[b0 * HH + u0 + r] = c0;
        cbuf[b1 * HH + u0 + r] = c1;
    }
}

// ---------------------------------------------------------------------------
__global__ void fc_kernel(const float* __restrict__ h2,
                          const float* __restrict__ Wfc,
                          const float* __restrict__ bfc,
                          float* __restrict__ out)
{
    __shared__ float hs[256];
    int b = blockIdx.x, tid = threadIdx.x;
    hs[tid] = h2[b * HH + tid];
    __syncthreads();
    if (tid < NC) {
        float s = bfc[tid];
        for (int k = 0; k < 256; k++) s += hs[k] * Wfc[tid * 256 + k];
        out[b * NC + tid] = s;
    }
}

// ---------------------------------------------------------------------------
extern "C" void kernel_launch(void* const* d_in, const int* in_sizes, int n_in,
                              void* d_out, int out_size, void* d_ws, size_t ws_size,
                              hipStream_t stream)
{
    const float* x    = (const float*)d_in[0];
    const float* Wih0 = (const float*)d_in[1];
    const float* Whh0 = (const float*)d_in[2];
    const float* bih0 = (const float*)d_in[3];
    const float* bhh0 = (const float*)d_in[4];
    const float* Wih1 = (const float*)d_in[5];
    const float* Whh1 = (const float*)d_in[6];
    const float* bih1 = (const float*)d_in[7];
    const float* bhh1 = (const float*)d_in[8];
    const float* Wfc  = (const float*)d_in[9];
    const float* bfc  = (const float*)d_in[10];

    float* ws = (float*)d_ws;

    int TC = TT;
    while (TC > 128) {
        size_t need = ((size_t)TC * BB * H4 + 6 * BBHH + 4096) * 4;
        if (need <= ws_size) break;
        TC >>= 1;
    }

    float* gxb = ws;
    float* h1r = gxb + (size_t)TC * BB * H4;
    float* h2r = h1r + 2 * BBHH;
    float* c1b = h2r + 2 * BBHH;
    float* c2b = c1b + BBHH;
    uintptr_t fp = ((uintptr_t)(c2b + BBHH) + 127) & ~(uintptr_t)127;
    Line* leaf  = (Line*)fp;           // NLEAF lines
    Line* rootc = leaf + NLEAF;        // 1 line
    Line* phl   = rootc + 1;           // 1 line

    // zero rings + cell states once
    hipMemsetAsync(h1r, 0, (size_t)6 * BBHH * 4, stream);

    const int nchunk = TT / TC;
    for (int ch = 0; ch < nchunk; ch++) {
        int t0 = ch * TC;
        dim3 gg(8, TC * 64 / 128);
        gemm_gx<<<gg, 256, 0, stream>>>(x, Wih0, bih0, bhh0, gxb, t0);
        hipMemsetAsync(leaf, 0, sizeof(Line) * (NLEAF + 2), stream);
        int last = (ch == nchunk - 1) ? 1 : 0;
        lstm_rec2<<<NWGT, 256, 0, stream>>>(gxb, Whh0, Wih1, Whh1, bih1, bhh1,
                                            h1r, h2r, c1b, c2b,
                                            leaf, rootc, phl,
                                            t0, TC, TC + last);
    }

    fc_kernel<<<BB, 256, 0, stream>>>(h2r + (size_t)((TT - 1) & 1) * BBHH,
                                      Wfc, bfc, (float*)d_out);
}

// Round 5
// 27742.255 us; speedup vs baseline: 3.0800x; 1.2684x over previous
//
#include <hip/hip_runtime.h>
#include <hip/hip_bf16.h>

#define BB 64
#define TT 2048
#define HH 256
#define H4 1024
#define NC 10
#define NWG1 128          // layer-1 WGs
#define NWGT 256          // total WGs (128 layer-1 + 128 layer-2)
#define NLEAF 32
#define BBHH (BB * HH)

struct __align__(128) Line { unsigned v; unsigned pad[31]; };  // one cacheline

__device__ __forceinline__ float sigmoidf_(float x) {
    return 1.0f / (1.0f + expf(-x));
}

// ---------------------------------------------------------------------------
// gx GEMM (layer 1 input contribution only):
// gx[tc][n][b] = sum_k x[b][t0+tc][k] * W[n][k] + bih[n] + bhh[n]
// ---------------------------------------------------------------------------
__global__ __launch_bounds__(256, 2)
void gemm_gx(const float* __restrict__ A, const float* __restrict__ W,
             const float* __restrict__ bias1, const float* __restrict__ bias2,
             float* __restrict__ gx, int t0)
{
    __shared__ float As[8][132];
    __shared__ float Bs[8][132];
    const int tid = threadIdx.x;
    const int m0 = blockIdx.y * 128, n0 = blockIdx.x * 128;
    const int tx = tid & 15, ty = tid >> 4;

    float acc[8][8];
#pragma unroll
    for (int i = 0; i < 8; i++)
#pragma unroll
        for (int j = 0; j < 8; j++) acc[i][j] = 0.f;

    const int mL = tid >> 1, half = tid & 1;
    const int gm = m0 + mL;
    const int b = gm & 63, tc = gm >> 6;
    const float* arow = A + ((size_t)b * TT + t0 + tc) * 256;
    const float* brow = W + (size_t)(n0 + mL) * 256;

    for (int k0 = 0; k0 < 256; k0 += 8) {
        float4 av = *(const float4*)(arow + k0 + half * 4);
        float4 bv = *(const float4*)(brow + k0 + half * 4);
        __syncthreads();
        As[half * 4 + 0][mL] = av.x; As[half * 4 + 1][mL] = av.y;
        As[half * 4 + 2][mL] = av.z; As[half * 4 + 3][mL] = av.w;
        Bs[half * 4 + 0][mL] = bv.x; Bs[half * 4 + 1][mL] = bv.y;
        Bs[half * 4 + 2][mL] = bv.z; Bs[half * 4 + 3][mL] = bv.w;
        __syncthreads();
#pragma unroll
        for (int k = 0; k < 8; k++) {
            float a[8], w[8];
            *(float4*)&a[0] = *(const float4*)&As[k][ty * 8];
            *(float4*)&a[4] = *(const float4*)&As[k][ty * 8 + 4];
            *(float4*)&w[0] = *(const float4*)&Bs[k][tx * 8];
            *(float4*)&w[4] = *(const float4*)&Bs[k][tx * 8 + 4];
#pragma unroll
            for (int i = 0; i < 8; i++)
#pragma unroll
                for (int j = 0; j < 8; j++) acc[i][j] += a[i] * w[j];
        }
    }
#pragma unroll
    for (int i = 0; i < 8; i++) {
        int m = m0 + ty * 8 + i;
        int bb = m & 63, tcc = m >> 6;
#pragma unroll
        for (int j = 0; j < 8; j++) {
            int n = n0 + tx * 8 + j;
            gx[((size_t)tcc * H4 + n) * 64 + bb] = acc[i][j] + bias1[n] + bias2[n];
        }
    }
}

// ---------------------------------------------------------------------------
// Merged persistent kernel. WGs [0,128) = layer 1, [128,256) = layer 2
// (one step behind). h published via relaxed agent-scope atomic stores
// (write-through to device coherence point -> NO release fence / wbl2).
// __syncthreads before arrival drains vmcnt, so h is visible before the
// arrival RMW. One acquire fence per WG per step (post-poll) keeps the
// normal cached staging loads coherent.
// ---------------------------------------------------------------------------
__global__ __launch_bounds__(256, 1)
void lstm_rec2(const float* __restrict__ gx, const float* __restrict__ Whh0,
               const float* __restrict__ Wih1, const float* __restrict__ Whh1,
               const float* __restrict__ bih1, const float* __restrict__ bhh1,
               float* __restrict__ h1r, float* __restrict__ h2r,
               float* __restrict__ c1b, float* __restrict__ c2b,
               Line* __restrict__ leaf, Line* __restrict__ rootc,
               Line* __restrict__ phl,
               int t0, int l1cnt, int niter)
{
    __shared__ float Wl[2][8][264];   // [0]=Whh0 (L1) or Wih1 (L2); [1]=Whh1 (L2)
    __shared__ float hA[64][260];     // h1_{i-1} stage (both layers)
    __shared__ float hB[64][260];     // h2_{i-2} stage (layer 2 only)

    const int tid = threadIdx.x;
    const int wg = blockIdx.x;
    const bool isL2 = wg >= NWG1;
    const int u0 = (isL2 ? wg - NWG1 : wg) * 2;
    const int r = tid & 7, duo = tid >> 3;
    const int b0 = 2 * duo, b1 = 2 * duo + 1;
    const int ul = r & 1;
    const int grow = (r >> 1) * HH + u0 + ul;

    {
        const float* W0 = isL2 ? Wih1 : Whh0;
#pragma unroll
        for (int rep = 0; rep < 2; rep++) {
            int idx = rep * 256 + tid;
            int row = idx >> 6, q = idx & 63;
            int gr = (row >> 1) * HH + u0 + (row & 1);
            *(float4*)&Wl[0][row][q * 4] = *(const float4*)(W0 + (size_t)gr * 256 + q * 4);
            if (isL2)
                *(float4*)&Wl[1][row][q * 4] = *(const float4*)(Whh1 + (size_t)gr * 256 + q * 4);
        }
    }
    float bs = 0.f;
    if (isL2) bs = bih1[grow] + bhh1[grow];

    float* cbuf = isL2 ? c2b : c1b;
    float c0 = 0.f, c1 = 0.f;
    if (r < 2) {
        c0 = cbuf[b0 * HH + u0 + r];
        c1 = cbuf[b1 * HH + u0 + r];
    }

    const int lane = tid & 63;
    const int sbase = ((lane >> 3) << 3) + ul;

    for (int j = 0; j < niter; j++) {
        const int i = t0 + j;
        const bool actL1 = (!isL2) && (j < l1cnt);
        const bool actL2 = isL2 && (i >= 1);

        // prefetch gx into registers BEFORE the barrier's acquire fence
        float gxa = 0.f, gxb_ = 0.f;
        if (actL1) {
            gxa  = gx[((size_t)j * H4 + grow) * BB + b0];
            gxb_ = gx[((size_t)j * H4 + grow) * BB + b1];
        }

        const float* srcA = h1r + (size_t)((i + 1) & 1) * BBHH;
        const float* srcB = h2r + (size_t)(i & 1) * BBHH;
#pragma unroll
        for (int rep = 0; rep < 16; rep++) {
            int idx = rep * 256 + tid;
            int bb = idx >> 6, q = idx & 63;
            float4 vA = *(const float4*)(srcA + bb * HH + q * 4);
            *(float4*)&hA[bb][q * 4] = vA;
            if (isL2) {
                float4 vB = *(const float4*)(srcB + bb * HH + q * 4);
                *(float4*)&hB[bb][q * 4] = vB;
            }
        }
        __syncthreads();

        float pre0 = 0.f, pre1 = 0.f;
        if (actL1) {
            float a0 = 0.f, a1 = 0.f;
#pragma unroll 8
            for (int k = 0; k < 256; k += 4) {
                float4 w  = *(const float4*)&Wl[0][r][k];
                float4 x0 = *(const float4*)&hA[b0][k];
                float4 x1 = *(const float4*)&hA[b1][k];
                a0 += w.x * x0.x + w.y * x0.y + w.z * x0.z + w.w * x0.w;
                a1 += w.x * x1.x + w.y * x1.y + w.z * x1.z + w.w * x1.w;
            }
            pre0 = a0 + gxa;
            pre1 = a1 + gxb_;
        } else if (actL2) {
            float a0 = 0.f, a1 = 0.f;
#pragma unroll 4
            for (int k = 0; k < 256; k += 4) {
                float4 wI  = *(const float4*)&Wl[0][r][k];
                float4 wH  = *(const float4*)&Wl[1][r][k];
                float4 xA0 = *(const float4*)&hA[b0][k];
                float4 xA1 = *(const float4*)&hA[b1][k];
                float4 xB0 = *(const float4*)&hB[b0][k];
                float4 xB1 = *(const float4*)&hB[b1][k];
                a0 += wI.x * xA0.x + wI.y * xA0.y + wI.z * xA0.z + wI.w * xA0.w
                    + wH.x * xB0.x + wH.y * xB0.y + wH.z * xB0.z + wH.w * xB0.w;
                a1 += wI.x * xA1.x + wI.y * xA1.y + wI.z * xA1.z + wI.w * xA1.w
                    + wH.x * xB1.x + wH.y * xB1.y + wH.z * xB1.z + wH.w * xB1.w;
            }
            pre0 = a0 + bs;
            pre1 = a1 + bs;
        }

        if (actL1 || actL2) {
            float i0 = __shfl(pre0, sbase + 0, 64);
            float f0 = __shfl(pre0, sbase + 2, 64);
            float g0 = __shfl(pre0, sbase + 4, 64);
            float o0 = __shfl(pre0, sbase + 6, 64);
            float i1 = __shfl(pre1, sbase + 0, 64);
            float f1 = __shfl(pre1, sbase + 2, 64);
            float g1 = __shfl(pre1, sbase + 4, 64);
            float o1 = __shfl(pre1, sbase + 6, 64);

            if (r < 2) {
                float ia = sigmoidf_(i0), fa = sigmoidf_(f0);
                float ga = tanhf(g0),     oa = sigmoidf_(o0);
                c0 = fa * c0 + ia * ga;
                float h0 = oa * tanhf(c0);
                float ib = sigmoidf_(i1), fb = sigmoidf_(f1);
                float gb = tanhf(g1),     ob = sigmoidf_(o1);
                c1 = fb * c1 + ib * gb;
                float h1n = ob * tanhf(c1);
                float* dst = actL1 ? (h1r + (size_t)(i & 1) * BBHH)
                                   : (h2r + (size_t)((i + 1) & 1) * BBHH);
                // write-through publication: no release fence / wbl2 needed
                __hip_atomic_store(&dst[b0 * HH + u0 + r], h0,
                                   __ATOMIC_RELAXED, __HIP_MEMORY_SCOPE_AGENT);
                __hip_atomic_store(&dst[b1 * HH + u0 + r], h1n,
                                   __ATOMIC_RELAXED, __HIP_MEMORY_SCOPE_AGENT);
            }
        }

        // ---- device barrier: relaxed hierarchical arrival, acquire only ----
        const unsigned target = (unsigned)j + 1u;
        __syncthreads();   // drains vmcnt: all h atomic stores are agent-visible
        if (tid == 0) {
            unsigned a = __hip_atomic_fetch_add(&leaf[wg & (NLEAF - 1)].v, 1u,
                                                __ATOMIC_RELAXED,
                                                __HIP_MEMORY_SCOPE_AGENT);
            if (a == target * (NWGT / NLEAF) - 1u) {
                unsigned rr = __hip_atomic_fetch_add(&rootc->v, 1u,
                                                     __ATOMIC_RELAXED,
                                                     __HIP_MEMORY_SCOPE_AGENT);
                if (rr == target * NLEAF - 1u) {
                    __hip_atomic_store(&phl->v, target, __ATOMIC_RELAXED,
                                       __HIP_MEMORY_SCOPE_AGENT);
                }
            }
            // relaxed poll: NO per-iteration cache invalidate
            while (__hip_atomic_load(&phl->v, __ATOMIC_RELAXED,
                                     __HIP_MEMORY_SCOPE_AGENT) < target)
                __builtin_amdgcn_s_sleep(1);
            // one acquire per step: invalidate stale h lines for staging loads
            __builtin_amdgcn_fence(__ATOMIC_ACQUIRE, "agent");
        }
        __syncthreads();
    }

    if (r < 2) {
        cbuf[b0 * HH + u0 + r] = c0;
        cbuf[b1 * HH + u0 + r] = c1;
    }
}

// ---------------------------------------------------------------------------
__global__ void fc_kernel(const float* __restrict__ h2,
                          const float* __restrict__ Wfc,
                          const float* __restrict__ bfc,
                          float* __restrict__ out)
{
    __shared__ float hs[256];
    int b = blockIdx.x, tid = threadIdx.x;
    hs[tid] = h2[b * HH + tid];
    __syncthreads();
    if (tid < NC) {
        float s = bfc[tid];
        for (int k = 0; k < 256; k++) s += hs[k] * Wfc[tid * 256 + k];
        out[b * NC + tid] = s;
    }
}

// ---------------------------------------------------------------------------
extern "C" void kernel_launch(void* const* d_in, const int* in_sizes, int n_in,
                              void* d_out, int out_size, void* d_ws, size_t ws_size,
                              hipStream_t stream)
{
    const float* x    = (const float*)d_in[0];
    const float* Wih0 = (const float*)d_in[1];
    const float* Whh0 = (const float*)d_in[2];
    const float* bih0 = (const float*)d_in[3];
    const float* bhh0 = (const float*)d_in[4];
    const float* Wih1 = (const float*)d_in[5];
    const float* Whh1 = (const float*)d_in[6];
    const float* bih1 = (const float*)d_in[7];
    const float* bhh1 = (const float*)d_in[8];
    const float* Wfc  = (const float*)d_in[9];
    const float* bfc  = (const float*)d_in[10];

    float* ws = (float*)d_ws;

    int TC = TT;
    while (TC > 128) {
        size_t need = ((size_t)TC * BB * H4 + 6 * BBHH + 8192) * 4;
        if (need <= ws_size) break;
        TC >>= 1;
    }

    float* gxb = ws;
    float* h1r = gxb + (size_t)TC * BB * H4;
    float* h2r = h1r + 2 * BBHH;
    float* c1b = h2r + 2 * BBHH;
    float* c2b = c1b + BBHH;
    uintptr_t fp = ((uintptr_t)(c2b + BBHH) + 127) & ~(uintptr_t)127;
    Line* leaf  = (Line*)fp;           // NLEAF lines
    Line* rootc = leaf + NLEAF;        // 1 line
    Line* phl   = rootc + 1;           // 1 line

    // zero rings + cell states once
    hipMemsetAsync(h1r, 0, (size_t)6 * BBHH * 4, stream);

    const int nchunk = TT / TC;
    for (int ch = 0; ch < nchunk; ch++) {
        int t0 = ch * TC;
        dim3 gg(8, TC * 64 / 128);
        gemm_gx<<<gg, 256, 0, stream>>>(x, Wih0, bih0, bhh0, gxb, t0);
        hipMemsetAsync(leaf, 0, sizeof(Line) * (NLEAF + 2), stream);
        int last = (ch == nchunk - 1) ? 1 : 0;
        lstm_rec2<<<NWGT, 256, 0, stream>>>(gxb, Whh0, Wih1, Whh1, bih1, bhh1,
                                            h1r, h2r, c1b, c2b,
                                            leaf, rootc, phl,
                                            t0, TC, TC + last);
    }

    fc_kernel<<<BB, 256, 0, stream>>>(h2r + (size_t)((TT - 1) & 1) * BBHH,
                                      Wfc, bfc, (float*)d_out);
}